// Round 1
// baseline (441.598 us; speedup 1.0000x reference)
//
#include <hip/hip_runtime.h>

typedef unsigned short u16;
typedef __bf16 bf16x8 __attribute__((ext_vector_type(8)));
typedef float f32x4 __attribute__((ext_vector_type(4)));

union U4B8 { uint4 u; bf16x8 v; u16 s[8]; };

__device__ __forceinline__ u16 f2b(float f) {
  union { float f; unsigned u; } x; x.f = f;
  unsigned u = x.u + 0x7fffu + ((x.u >> 16) & 1u);
  return (u16)(u >> 16);
}

// ---------------- fp32 -> bf16 elementwise (for x) ----------------
__global__ __launch_bounds__(256) void cvt_f32_bf16(const float* __restrict__ in,
                                                    u16* __restrict__ out) {
  int i = blockIdx.x * 256 + threadIdx.x;
  float4 v = ((const float4*)in)[i];
  ushort4 h;
  h.x = f2b(v.x); h.y = f2b(v.y); h.z = f2b(v.z); h.w = f2b(v.w);
  ((ushort4*)out)[i] = h;
}

// ---------------- W [K][N] fp32 -> Wt [N][K] bf16 ----------------
__global__ __launch_bounds__(256) void transpose_w(const float* __restrict__ in,
                                                   u16* __restrict__ out, int K, int N) {
  __shared__ u16 t[64 * 72];
  int k0 = blockIdx.y * 64, n0 = blockIdx.x * 64;
  int tid = threadIdx.x;
#pragma unroll
  for (int p = 0; p < 4; ++p) {
    int idx = p * 256 + tid;        // 1024 float4 = 64 rows x 16 float4
    int k = idx >> 4, ng = idx & 15;
    float4 v = *(const float4*)(in + (k0 + k) * N + n0 + ng * 4);
    t[(ng * 4 + 0) * 72 + k] = f2b(v.x);
    t[(ng * 4 + 1) * 72 + k] = f2b(v.y);
    t[(ng * 4 + 2) * 72 + k] = f2b(v.z);
    t[(ng * 4 + 3) * 72 + k] = f2b(v.w);
  }
  __syncthreads();
#pragma unroll
  for (int p = 0; p < 2; ++p) {
    int idx = p * 256 + tid;        // 512 uint4 = 64 rows x 8 uint4
    int n = idx >> 3, kg = (idx & 7) * 8;
    uint4 u = *(uint4*)(&t[n * 72 + kg]);
    *(uint4*)(out + (n0 + n) * K + k0 + kg) = u;
  }
}

// ---------------- GEMM: C[M][N] = A[M][1024] @ Wt^T + bias ----------------
// A bf16 [M][1024], B = Wt bf16 [N][1024]. 128x128 tile, BK=32, 4 waves.
// MODE 0: N=3072, out -> Q/K/V bf16 [64][2048][64], q scaled by 0.125
// MODE 1: N=1024, out -> fp32 d_out
template <int MODE>
__global__ __launch_bounds__(256) void gemm_bf16(const u16* __restrict__ A,
                                                 const u16* __restrict__ B,
                                                 const float* __restrict__ bias,
                                                 float* __restrict__ outf,
                                                 u16* __restrict__ Qo, u16* __restrict__ Ko,
                                                 u16* __restrict__ Vo) {
  __shared__ u16 a_lds[128 * 40];
  __shared__ u16 b_lds[128 * 40];
  int tid = threadIdx.x;
  int l = tid & 63, w = tid >> 6;
  int wr = (w >> 1) * 64, wc = (w & 1) * 64;
  int m0 = blockIdx.y * 128, n0 = blockIdx.x * 128;
  int ka = (l >> 4) * 8;
  f32x4 acc[4][4] = {};
  for (int kt = 0; kt < 32; ++kt) {
    int k0 = kt * 32;
    __syncthreads();
#pragma unroll
    for (int p = 0; p < 2; ++p) {
      int idx = p * 256 + tid;
      int r = idx >> 2, kg = (idx & 3) * 8;
      *(uint4*)(&a_lds[r * 40 + kg]) = *(const uint4*)(A + (m0 + r) * 1024 + k0 + kg);
      *(uint4*)(&b_lds[r * 40 + kg]) = *(const uint4*)(B + (n0 + r) * 1024 + k0 + kg);
    }
    __syncthreads();
    bf16x8 af[4], bf[4];
#pragma unroll
    for (int i = 0; i < 4; ++i) {
      U4B8 ua; ua.u = *(uint4*)(&a_lds[(wr + i * 16 + (l & 15)) * 40 + ka]); af[i] = ua.v;
      U4B8 ub; ub.u = *(uint4*)(&b_lds[(wc + i * 16 + (l & 15)) * 40 + ka]); bf[i] = ub.v;
    }
#pragma unroll
    for (int i = 0; i < 4; ++i)
#pragma unroll
      for (int j = 0; j < 4; ++j)
        acc[i][j] = __builtin_amdgcn_mfma_f32_16x16x32_bf16(af[i], bf[j], acc[i][j], 0, 0, 0);
  }
  int rbase = (l >> 4) * 4;
#pragma unroll
  for (int i = 0; i < 4; ++i)
#pragma unroll
    for (int j = 0; j < 4; ++j) {
      int n = n0 + wc + j * 16 + (l & 15);
      float bv = bias[n];
#pragma unroll
      for (int r = 0; r < 4; ++r) {
        int m = m0 + wr + i * 16 + rbase + r;
        float val = acc[i][j][r] + bv;
        if (MODE == 0) {
          int h = n / 192, rem = n % 192;
          int part = rem >> 6, d = rem & 63;
          int b = m >> 11, s = m & 2047;
          int off = (((b * 16 + h) * 2048) + s) * 64 + d;
          u16 hv = f2b(part == 0 ? val * 0.125f : val);
          if (part == 0) Qo[off] = hv;
          else if (part == 1) Ko[off] = hv;
          else Vo[off] = hv;
        } else {
          outf[m * 1024 + n] = val;
        }
      }
    }
}

// ---------------- flash attention ----------------
// grid: (32 qblocks, 64 bh). block 256 = 4 waves, wave owns 16 q rows.
__global__ __launch_bounds__(256) void attn_fwd(const u16* __restrict__ Q,
                                                const u16* __restrict__ K,
                                                const u16* __restrict__ V,
                                                u16* __restrict__ O) {
  __shared__ u16 k_lds[64 * 72];
  __shared__ u16 vt_lds[64 * 72];
  __shared__ u16 p_lds[4 * 16 * 72];
  int tid = threadIdx.x;
  int l = tid & 63, w = tid >> 6;
  int qb = blockIdx.x, bh = blockIdx.y;
  int base = bh * 2048 * 64;
  int ka = (l >> 4) * 8;
  int rbase = (l >> 4) * 4;
  int qrow = qb * 64 + w * 16 + (l & 15);
  U4B8 uq0, uq1;
  uq0.u = *(const uint4*)(Q + base + qrow * 64 + ka);
  uq1.u = *(const uint4*)(Q + base + qrow * 64 + 32 + ka);
  bf16x8 qf0 = uq0.v, qf1 = uq1.v;
  float m_run[4], l_run[4];
  f32x4 o[4] = {};
#pragma unroll
  for (int j = 0; j < 4; ++j) { m_run[j] = -1e30f; l_run[j] = 0.f; }
  u16* pw = p_lds + w * 16 * 72;
  for (int t = 0; t < 32; ++t) {
    __syncthreads();
    int kv0 = t * 64;
#pragma unroll
    for (int p = 0; p < 2; ++p) {
      int idx = p * 256 + tid;
      int r = idx >> 3, dg = (idx & 7) * 8;
      uint4 kvv = *(const uint4*)(K + base + (kv0 + r) * 64 + dg);
      *(uint4*)(&k_lds[r * 72 + dg]) = kvv;
      U4B8 uv; uv.u = *(const uint4*)(V + base + (kv0 + r) * 64 + dg);
#pragma unroll
      for (int i = 0; i < 8; ++i) vt_lds[(dg + i) * 72 + r] = uv.s[i];
    }
    __syncthreads();
    // S = (Q*scale) @ K^T  (scale pre-folded into Q)
    f32x4 s[4];
#pragma unroll
    for (int c = 0; c < 4; ++c) {
      f32x4 z = {};
      U4B8 uk;
      uk.u = *(uint4*)(&k_lds[(c * 16 + (l & 15)) * 72 + ka]);
      z = __builtin_amdgcn_mfma_f32_16x16x32_bf16(qf0, uk.v, z, 0, 0, 0);
      uk.u = *(uint4*)(&k_lds[(c * 16 + (l & 15)) * 72 + 32 + ka]);
      z = __builtin_amdgcn_mfma_f32_16x16x32_bf16(qf1, uk.v, z, 0, 0, 0);
      s[c] = z;
    }
    // online softmax: lane holds rows rbase+j, col = c*16 + (l&15)
    float mnew[4], alpha[4], rs[4];
#pragma unroll
    for (int j = 0; j < 4; ++j) {
      float mx = fmaxf(fmaxf(s[0][j], s[1][j]), fmaxf(s[2][j], s[3][j]));
#pragma unroll
      for (int mk = 1; mk < 16; mk <<= 1) mx = fmaxf(mx, __shfl_xor(mx, mk));
      mnew[j] = fmaxf(m_run[j], mx);
      alpha[j] = __expf(m_run[j] - mnew[j]);
      m_run[j] = mnew[j];
      rs[j] = 0.f;
    }
#pragma unroll
    for (int c = 0; c < 4; ++c)
#pragma unroll
      for (int j = 0; j < 4; ++j) {
        float p = __expf(s[c][j] - mnew[j]);
        rs[j] += p;
        pw[(rbase + j) * 72 + c * 16 + (l & 15)] = f2b(p);
      }
#pragma unroll
    for (int j = 0; j < 4; ++j) {
      float sv = rs[j];
#pragma unroll
      for (int mk = 1; mk < 16; mk <<= 1) sv += __shfl_xor(sv, mk);
      l_run[j] = l_run[j] * alpha[j] + sv;
    }
#pragma unroll
    for (int c = 0; c < 4; ++c)
#pragma unroll
      for (int j = 0; j < 4; ++j) o[c][j] *= alpha[j];
    // O += P @ V
#pragma unroll
    for (int c2 = 0; c2 < 4; ++c2) {
      U4B8 up, uv2;
      up.u = *(uint4*)(&pw[(l & 15) * 72 + ka]);
      uv2.u = *(uint4*)(&vt_lds[(c2 * 16 + (l & 15)) * 72 + ka]);
      o[c2] = __builtin_amdgcn_mfma_f32_16x16x32_bf16(up.v, uv2.v, o[c2], 0, 0, 0);
      up.u = *(uint4*)(&pw[(l & 15) * 72 + 32 + ka]);
      uv2.u = *(uint4*)(&vt_lds[(c2 * 16 + (l & 15)) * 72 + 32 + ka]);
      o[c2] = __builtin_amdgcn_mfma_f32_16x16x32_bf16(up.v, uv2.v, o[c2], 0, 0, 0);
    }
  }
  int b = bh >> 4, h = bh & 15;
#pragma unroll
  for (int j = 0; j < 4; ++j) {
    float inv = 1.f / l_run[j];
    int sq = qb * 64 + w * 16 + rbase + j;
    int rowoff = (b * 2048 + sq) * 1024 + h * 64;
#pragma unroll
    for (int c = 0; c < 4; ++c) O[rowoff + c * 16 + (l & 15)] = f2b(o[c][j] * inv);
  }
}

extern "C" void kernel_launch(void* const* d_in, const int* in_sizes, int n_in,
                              void* d_out, int out_size, void* d_ws, size_t ws_size,
                              hipStream_t stream) {
  const float* x = (const float*)d_in[0];
  const float* Wqkv = (const float*)d_in[1];
  const float* bqkv = (const float*)d_in[2];
  const float* Wout = (const float*)d_in[3];
  const float* bout = (const float*)d_in[4];
  float* out = (float*)d_out;

  u16* ws = (u16*)d_ws;
  u16* WtQ = ws;                    // 3072*1024
  u16* WtO = WtQ + 3072 * 1024;     // 1024*1024
  u16* Xb  = WtO + 1024 * 1024;     // 8192*1024
  u16* Qw  = Xb + 8192 * 1024;      // 64*2048*64
  u16* Kw  = Qw + 64 * 2048 * 64;
  u16* Vw  = Kw + 64 * 2048 * 64;
  u16* Aw  = Vw + 64 * 2048 * 64;   // 8192*1024

  cvt_f32_bf16<<<8192, 256, 0, stream>>>(x, Xb);
  transpose_w<<<dim3(48, 16), 256, 0, stream>>>(Wqkv, WtQ, 1024, 3072);
  transpose_w<<<dim3(16, 16), 256, 0, stream>>>(Wout, WtO, 1024, 1024);
  gemm_bf16<0><<<dim3(24, 64), 256, 0, stream>>>(Xb, WtQ, bqkv, nullptr, Qw, Kw, Vw);
  attn_fwd<<<dim3(32, 64), 256, 0, stream>>>(Qw, Kw, Vw, Aw);
  gemm_bf16<1><<<dim3(8, 64), 256, 0, stream>>>(Aw, WtO, bout, out, nullptr, nullptr, nullptr);
}

// Round 2
// 352.188 us; speedup vs baseline: 1.2539x; 1.2539x over previous
//
#include <hip/hip_runtime.h>

typedef unsigned short u16;
typedef __bf16 bf16x8 __attribute__((ext_vector_type(8)));
typedef float f32x4 __attribute__((ext_vector_type(4)));

union U4B8 { uint4 u; bf16x8 v; u16 s[8]; };

__device__ __forceinline__ u16 f2b(float f) {
  union { float f; unsigned u; } x; x.f = f;
  unsigned u = x.u + 0x7fffu + ((x.u >> 16) & 1u);
  return (u16)(u >> 16);
}

// ---------------- fp32 -> bf16 elementwise (for x) ----------------
__global__ __launch_bounds__(256) void cvt_f32_bf16(const float* __restrict__ in,
                                                    u16* __restrict__ out) {
  int i = blockIdx.x * 256 + threadIdx.x;
  float4 v = ((const float4*)in)[i];
  ushort4 h;
  h.x = f2b(v.x); h.y = f2b(v.y); h.z = f2b(v.z); h.w = f2b(v.w);
  ((ushort4*)out)[i] = h;
}

// ---------------- W [K][N] fp32 -> Wt [N][K] bf16 ----------------
__global__ __launch_bounds__(256) void transpose_w(const float* __restrict__ in,
                                                   u16* __restrict__ out, int K, int N) {
  __shared__ u16 t[64 * 72];
  int k0 = blockIdx.y * 64, n0 = blockIdx.x * 64;
  int tid = threadIdx.x;
#pragma unroll
  for (int p = 0; p < 4; ++p) {
    int idx = p * 256 + tid;        // 1024 float4 = 64 rows x 16 float4
    int k = idx >> 4, ng = idx & 15;
    float4 v = *(const float4*)(in + (k0 + k) * N + n0 + ng * 4);
    t[(ng * 4 + 0) * 72 + k] = f2b(v.x);
    t[(ng * 4 + 1) * 72 + k] = f2b(v.y);
    t[(ng * 4 + 2) * 72 + k] = f2b(v.z);
    t[(ng * 4 + 3) * 72 + k] = f2b(v.w);
  }
  __syncthreads();
#pragma unroll
  for (int p = 0; p < 2; ++p) {
    int idx = p * 256 + tid;        // 512 uint4 = 64 rows x 8 uint4
    int n = idx >> 3, kg = (idx & 7) * 8;
    uint4 u = *(uint4*)(&t[n * 72 + kg]);
    *(uint4*)(out + (n0 + n) * K + k0 + kg) = u;
  }
}

// ---------------- GEMM: C[M][N] = A[M][1024] @ Wt^T + bias ----------------
// A bf16 [M][1024], B = Wt bf16 [N][1024]. 128x128 tile, BK=32, 4 waves.
// Staging via global_load_lds width=16, unpadded [128][32] LDS tiles.
// MODE 0: N=3072, out -> Q/K/V bf16 [64][2048][64], q scaled by 0.125
// MODE 1: N=1024, out -> fp32 d_out
template <int MODE>
__global__ __launch_bounds__(256) void gemm_bf16(const u16* __restrict__ A,
                                                 const u16* __restrict__ B,
                                                 const float* __restrict__ bias,
                                                 float* __restrict__ outf,
                                                 u16* __restrict__ Qo, u16* __restrict__ Ko,
                                                 u16* __restrict__ Vo) {
  __shared__ u16 a_lds[128 * 32];
  __shared__ u16 b_lds[128 * 32];
  int tid = threadIdx.x;
  int l = tid & 63, w = tid >> 6;
  int wr = (w >> 1) * 64, wc = (w & 1) * 64;
  int m0 = blockIdx.y * 128, n0 = blockIdx.x * 128;
  int r15 = l & 15;
  int ka = (l >> 4) * 8;
  int r0 = tid >> 2, kg0 = (tid & 3) * 8;   // staging: row r0 (round 0), r0+64 (round 1)
  f32x4 acc[4][4] = {};
  for (int kt = 0; kt < 32; ++kt) {
    int k0 = kt * 32;
    __syncthreads();
    __builtin_amdgcn_global_load_lds(
        (const __attribute__((address_space(1))) void*)(A + (m0 + r0) * 1024 + k0 + kg0),
        (__attribute__((address_space(3))) void*)(&a_lds[tid * 8]), 16, 0, 0);
    __builtin_amdgcn_global_load_lds(
        (const __attribute__((address_space(1))) void*)(A + (m0 + 64 + r0) * 1024 + k0 + kg0),
        (__attribute__((address_space(3))) void*)(&a_lds[2048 + tid * 8]), 16, 0, 0);
    __builtin_amdgcn_global_load_lds(
        (const __attribute__((address_space(1))) void*)(B + (n0 + r0) * 1024 + k0 + kg0),
        (__attribute__((address_space(3))) void*)(&b_lds[tid * 8]), 16, 0, 0);
    __builtin_amdgcn_global_load_lds(
        (const __attribute__((address_space(1))) void*)(B + (n0 + 64 + r0) * 1024 + k0 + kg0),
        (__attribute__((address_space(3))) void*)(&b_lds[2048 + tid * 8]), 16, 0, 0);
    __syncthreads();
    bf16x8 af[4], bf[4];
#pragma unroll
    for (int i = 0; i < 4; ++i) {
      U4B8 ua; ua.u = *(uint4*)(&a_lds[(wr + i * 16 + r15) * 32 + ka]); af[i] = ua.v;
      U4B8 ub; ub.u = *(uint4*)(&b_lds[(wc + i * 16 + r15) * 32 + ka]); bf[i] = ub.v;
    }
#pragma unroll
    for (int i = 0; i < 4; ++i)
#pragma unroll
      for (int j = 0; j < 4; ++j)
        acc[i][j] = __builtin_amdgcn_mfma_f32_16x16x32_bf16(af[i], bf[j], acc[i][j], 0, 0, 0);
  }
  int rbase = (l >> 4) * 4;
#pragma unroll
  for (int i = 0; i < 4; ++i)
#pragma unroll
    for (int j = 0; j < 4; ++j) {
      int n = n0 + wc + j * 16 + r15;
      float bv = bias[n];
#pragma unroll
      for (int r = 0; r < 4; ++r) {
        int m = m0 + wr + i * 16 + rbase + r;
        float val = acc[i][j][r] + bv;
        if (MODE == 0) {
          int h = n / 192, rem = n % 192;
          int part = rem >> 6, d = rem & 63;
          int b = m >> 11, s = m & 2047;
          int off = (((b * 16 + h) * 2048) + s) * 64 + d;
          u16 hv = f2b(part == 0 ? val * 0.125f : val);
          if (part == 0) Qo[off] = hv;
          else if (part == 1) Ko[off] = hv;
          else Vo[off] = hv;
        } else {
          outf[m * 1024 + n] = val;
        }
      }
    }
}

// ---------------- flash attention (swapped QK^T, in-register softmax) ----------------
// grid: (32 qblocks, 64 bh). block 256 = 4 waves, wave owns 16 q rows.
// S^T = mfma(K_tile, Q): lane l holds S^T[kv=16c+4g+j][q=l&15] -> per-lane row softmax.
// P stored per-wave [16 q][72] (b64 writes, b128 A-frag reads).
// V^T in LDS [64 d][72] with elem-XOR ((d>>3)&7)<<3 swizzle: conflict-free scalar
// transpose-writes, uniform b128 reads. K/V double-buffered, 1 barrier/tile.
__global__ __launch_bounds__(256) void attn_fwd(const u16* __restrict__ Q,
                                                const u16* __restrict__ K,
                                                const u16* __restrict__ V,
                                                u16* __restrict__ O) {
  __shared__ u16 k_lds[2 * 64 * 72];
  __shared__ u16 vt_lds[2 * 64 * 72];
  __shared__ u16 p_lds[4 * 16 * 72];
  int tid = threadIdx.x;
  int l = tid & 63, w = tid >> 6;
  int g = l >> 4, r15 = l & 15;
  int qb = blockIdx.x, bh = blockIdx.y;
  const u16* Kb = K + bh * 2048 * 64;
  const u16* Vb = V + bh * 2048 * 64;
  int ka = g * 8;
  // Q B-frag: lane holds Q[q=r15][ka..ka+7] (+32) for the wave's 16 q rows
  int qrow = qb * 64 + w * 16 + r15;
  U4B8 uq0, uq1;
  uq0.u = *(const uint4*)(Q + bh * 2048 * 64 + qrow * 64 + ka);
  uq1.u = *(const uint4*)(Q + bh * 2048 * 64 + qrow * 64 + 32 + ka);
  bf16x8 qf0 = uq0.v, qf1 = uq1.v;

  // staging decomposition: idx = p*256+tid -> r = idx>>3 (kv row), dgi = idx&7, dg = dgi*8
  int sr0 = tid >> 3, sdgi = tid & 7, sdg = sdgi * 8;
  int sr1 = sr0 + 32;

  U4B8 kreg[2], vreg[2];
#define STAGE_LOAD(T)                                                   \
  {                                                                     \
    int kv0 = (T) * 64;                                                 \
    kreg[0].u = *(const uint4*)(Kb + (kv0 + sr0) * 64 + sdg);           \
    vreg[0].u = *(const uint4*)(Vb + (kv0 + sr0) * 64 + sdg);           \
    kreg[1].u = *(const uint4*)(Kb + (kv0 + sr1) * 64 + sdg);           \
    vreg[1].u = *(const uint4*)(Vb + (kv0 + sr1) * 64 + sdg);           \
  }
#define STAGE_WRITE(BUF)                                                \
  {                                                                     \
    u16* kd = k_lds + (BUF) * (64 * 72);                                \
    u16* vd = vt_lds + (BUF) * (64 * 72);                               \
    *(uint4*)(&kd[sr0 * 72 + sdg]) = kreg[0].u;                         \
    *(uint4*)(&kd[sr1 * 72 + sdg]) = kreg[1].u;                         \
    int sw = sdgi << 3;                                                 \
    _Pragma("unroll")                                                   \
    for (int i = 0; i < 8; ++i) {                                       \
      vd[(((sdg + i) * 72 + sr0)) ^ sw] = vreg[0].s[i];                 \
      vd[(((sdg + i) * 72 + sr1)) ^ sw] = vreg[1].s[i];                 \
    }                                                                   \
  }

  STAGE_LOAD(0);
  STAGE_WRITE(0);

  float m_run = -1e30f, l_run = 0.f;   // state for q row r15 (dup x4 across g)
  f32x4 o[4] = {};                     // o[dq][j] = O[q=4g+j][d=dq*16+r15]
  u16* pw = p_lds + w * (16 * 72);

  for (int t = 0; t < 32; ++t) {
    int cur = t & 1;
    if (t < 31) STAGE_LOAD(t + 1);
    __syncthreads();
    const u16* kc = k_lds + cur * (64 * 72);
    const u16* vc = vt_lds + cur * (64 * 72);
    // S^T = K_tile @ Q^T
    f32x4 s[4];
#pragma unroll
    for (int c = 0; c < 4; ++c) {
      U4B8 k0, k1;
      k0.u = *(const uint4*)(kc + (c * 16 + r15) * 72 + ka);
      k1.u = *(const uint4*)(kc + (c * 16 + r15) * 72 + 32 + ka);
      f32x4 z = {};
      z = __builtin_amdgcn_mfma_f32_16x16x32_bf16(k0.v, qf0, z, 0, 0, 0);
      z = __builtin_amdgcn_mfma_f32_16x16x32_bf16(k1.v, qf1, z, 0, 0, 0);
      s[c] = z;
    }
    // online softmax, row = r15 (lane-local 16 values, + 2 shfl to combine g groups)
    float mx = s[0][0];
#pragma unroll
    for (int c = 0; c < 4; ++c)
#pragma unroll
      for (int j = 0; j < 4; ++j) mx = fmaxf(mx, s[c][j]);
    mx = fmaxf(mx, __shfl_xor(mx, 16));
    mx = fmaxf(mx, __shfl_xor(mx, 32));
    float mnew = fmaxf(m_run, mx);
    float alpha = __expf(m_run - mnew);
    m_run = mnew;
    float rs = 0.f;
    u16* pwr = pw + r15 * 72 + 4 * g;
#pragma unroll
    for (int c = 0; c < 4; ++c) {
      float p0 = __expf(s[c][0] - mnew);
      float p1 = __expf(s[c][1] - mnew);
      float p2 = __expf(s[c][2] - mnew);
      float p3 = __expf(s[c][3] - mnew);
      rs += (p0 + p1) + (p2 + p3);
      ushort4 h;
      h.x = f2b(p0); h.y = f2b(p1); h.z = f2b(p2); h.w = f2b(p3);
      *(ushort4*)(pwr + c * 16) = h;   // P[q=r15][kv=16c+4g .. +3]
    }
    rs += __shfl_xor(rs, 16);
    rs += __shfl_xor(rs, 32);
    l_run = l_run * alpha + rs;
    // rescale O: need alpha of row 4g+j (lives in lanes with r15 == 4g+j)
    float aj0 = __shfl(alpha, 4 * g + 0);
    float aj1 = __shfl(alpha, 4 * g + 1);
    float aj2 = __shfl(alpha, 4 * g + 2);
    float aj3 = __shfl(alpha, 4 * g + 3);
#pragma unroll
    for (int dq = 0; dq < 4; ++dq) {
      o[dq][0] *= aj0; o[dq][1] *= aj1; o[dq][2] *= aj2; o[dq][3] *= aj3;
    }
    // O += P @ V
    U4B8 pa0, pa1;
    pa0.u = *(const uint4*)(pw + r15 * 72 + ka);
    pa1.u = *(const uint4*)(pw + r15 * 72 + 32 + ka);
#pragma unroll
    for (int dq = 0; dq < 4; ++dq) {
      int d = dq * 16 + r15;
      int sw = ((d >> 3) & 7) << 3;
      U4B8 v0, v1;
      v0.u = *(const uint4*)(vc + ((d * 72 + ka) ^ sw));
      v1.u = *(const uint4*)(vc + ((d * 72 + 32 + ka) ^ sw));
      o[dq] = __builtin_amdgcn_mfma_f32_16x16x32_bf16(pa0.v, v0.v, o[dq], 0, 0, 0);
      o[dq] = __builtin_amdgcn_mfma_f32_16x16x32_bf16(pa1.v, v1.v, o[dq], 0, 0, 0);
    }
    if (t < 31) STAGE_WRITE(cur ^ 1);
  }
#undef STAGE_LOAD
#undef STAGE_WRITE

  float inv = 1.f / l_run;
  float ij0 = __shfl(inv, 4 * g + 0);
  float ij1 = __shfl(inv, 4 * g + 1);
  float ij2 = __shfl(inv, 4 * g + 2);
  float ij3 = __shfl(inv, 4 * g + 3);
  float ij[4] = {ij0, ij1, ij2, ij3};
  int b = bh >> 4, h = bh & 15;
#pragma unroll
  for (int j = 0; j < 4; ++j) {
    int sq = qb * 64 + w * 16 + 4 * g + j;
    int rowoff = (b * 2048 + sq) * 1024 + h * 64;
#pragma unroll
    for (int dq = 0; dq < 4; ++dq) O[rowoff + dq * 16 + r15] = f2b(o[dq][j] * ij[j]);
  }
}

extern "C" void kernel_launch(void* const* d_in, const int* in_sizes, int n_in,
                              void* d_out, int out_size, void* d_ws, size_t ws_size,
                              hipStream_t stream) {
  const float* x = (const float*)d_in[0];
  const float* Wqkv = (const float*)d_in[1];
  const float* bqkv = (const float*)d_in[2];
  const float* Wout = (const float*)d_in[3];
  const float* bout = (const float*)d_in[4];
  float* out = (float*)d_out;

  u16* ws = (u16*)d_ws;
  u16* WtQ = ws;                    // 3072*1024
  u16* WtO = WtQ + 3072 * 1024;     // 1024*1024
  u16* Xb  = WtO + 1024 * 1024;     // 8192*1024
  u16* Qw  = Xb + 8192 * 1024;      // 64*2048*64
  u16* Kw  = Qw + 64 * 2048 * 64;
  u16* Vw  = Kw + 64 * 2048 * 64;
  u16* Aw  = Vw + 64 * 2048 * 64;   // 8192*1024

  cvt_f32_bf16<<<8192, 256, 0, stream>>>(x, Xb);
  transpose_w<<<dim3(48, 16), 256, 0, stream>>>(Wqkv, WtQ, 1024, 3072);
  transpose_w<<<dim3(16, 16), 256, 0, stream>>>(Wout, WtO, 1024, 1024);
  gemm_bf16<0><<<dim3(24, 64), 256, 0, stream>>>(Xb, WtQ, bqkv, nullptr, Qw, Kw, Vw);
  attn_fwd<<<dim3(32, 64), 256, 0, stream>>>(Qw, Kw, Vw, Aw);
  gemm_bf16<1><<<dim3(8, 64), 256, 0, stream>>>(Aw, WtO, bout, out, nullptr, nullptr, nullptr);
}